// Round 10
// baseline (283.804 us; speedup 1.0000x reference)
//
#include <hip/hip_runtime.h>
#include <hip/hip_bf16.h>

// GCN GraphConv (norm='both', mult-first): out = relu( D_in^-1/2 * A * D_out^-1/2 * (X W) + b )
// N=100000 nodes, E=3200000 edges, IN=128, OUT=64, fp32 in/out.
//
// R21 = R20 with gather processing 2 nodes per wave (8 sxw loads in flight):
//  K1 pg: INTERLEAVED partition | gemm (R19/R20-verified, 86us, VGPR 40).
//  K2 cc: [0,NB) csr register-resident | [NB,2NB) count -> rsq_out (R20-verified).
//  K3 gather: wave owns nodes {2n, 2n+1}; fused main loops double MLP in the
//     deg~32 regime (mean deg = 32 -> old loop had just ONE 4-in-flight round).
//     Per-node accumulation order identical to R20 -> bitwise-same results.
// Lessons enforced: no per-edge global atomics (R16), no float4-W gemm (R17),
// no LDS f32 accumulation (R12/13), occupancy > micro-opts (R17/R18).

constexpr int N_NODES = 100000;
constexpr int N_EDGES = 3200000;
constexpr int IN_F    = 128;
constexpr int OUT_F   = 64;
constexpr int BUCKET_NODES = 256;
constexpr int NB   = (N_NODES + BUCKET_NODES - 1) / BUCKET_NODES;  // 391
constexpr int CAPB = 10240;          // bucket capacity; mean 8184, sd~90 -> 22 sigma
constexpr int C_CHUNK  = 4096;
constexpr int C_BLOCKS = (N_EDGES + C_CHUNK - 1) / C_CHUNK;        // 782 (last cn=1024, %4==0)
constexpr int G_TILE   = 32;         // gemm rows per block-iteration
constexpr int G_BLOCKS = 1024;
constexpr int G_GROUPS = N_NODES / G_TILE;                         // 3125
constexpr int PG_GRID  = 2 * C_BLOCKS + (G_BLOCKS - C_BLOCKS);     // 1806

// ---- Kernel 1 (pg): interleaved partition | gemm (R19/R20-identical) ----
__global__ __launch_bounds__(512) void pg_kernel(
        const int* __restrict__ src, const int* __restrict__ dst,
        int* __restrict__ bucket_cnt, int* __restrict__ bucket_cnt2,
        unsigned* __restrict__ pairs, unsigned char* __restrict__ sbytes,
        const float* __restrict__ x, const float* __restrict__ W,
        __hip_bfloat16* __restrict__ sxw) {
    alignas(16) __shared__ char smem[49408];   // partition 49408 | gemm 49152
    const int tid = threadIdx.x;
    const int bid = blockIdx.x;

    bool is_part;
    int  idx;
    if (bid < 2 * C_BLOCKS) { is_part = (bid & 1) == 0; idx = bid >> 1; }
    else                    { is_part = false; idx = C_BLOCKS + (bid - 2 * C_BLOCKS); }

    if (is_part) {
        // ---------------- partition path (R0-identical body) ----------------
        int* l_cnt   = (int*)smem;
        int* l_base  = l_cnt   + NB;
        int* l_pos   = l_base  + NB;
        int* g_base  = l_pos   + NB;
        int* l_cnt2  = g_base  + NB;
        int* l_base2 = l_cnt2  + NB;
        int* l_pos2  = l_base2 + NB;
        int* g_base2 = l_pos2  + NB;                         // ends @12512
        int* wsum_s  = g_base2 + NB;                         // 32 B @12512
        unsigned*       buf     = (unsigned*)(smem + 12544);       // 16384 B
        unsigned short* bkt_of  = (unsigned short*)(smem + 28928); // 8192 B
        unsigned char*  bbuf    = (unsigned char*)(smem + 37120);  // 4096 B
        unsigned short* bkt2_of = (unsigned short*)(smem + 41216); // 8192 B

        const int lane = tid & 63;
        const int wid  = tid >> 6;
        const long e0 = (long)idx * C_CHUNK;
        const int  cn = (int)min((long)C_CHUNK, (long)N_EDGES - e0);
        const int  cn4 = cn >> 2;

        for (int i = tid; i < NB; i += 512) { l_cnt[i] = 0; l_cnt2[i] = 0; }
        __syncthreads();

        unsigned r_pk[8];
        short    r_bk[8];
        const int4* d4p = (const int4*)(dst + e0);
        const int4* s4p = (const int4*)(src + e0);
        #pragma unroll
        for (int k = 0; k < 2; ++k) {
            int i4 = tid + k * 512;
            int rb = k * 4;
            if (i4 < cn4) {
                int4 d4 = d4p[i4];
                int4 s4 = s4p[i4];
                int dd[4] = {d4.x, d4.y, d4.z, d4.w};
                int ss[4] = {s4.x, s4.y, s4.z, s4.w};
                #pragma unroll
                for (int j = 0; j < 4; ++j) {
                    int bk = dd[j] >> 8;
                    r_bk[rb + j] = (short)bk;
                    r_pk[rb + j] = ((unsigned)(dd[j] & 255) << 17) | (unsigned)ss[j];
                    atomicAdd(&l_cnt[bk], 1);
                    atomicAdd(&l_cnt2[ss[j] >> 8], 1);
                }
            } else {
                #pragma unroll
                for (int j = 0; j < 4; ++j) r_bk[rb + j] = -1;
            }
        }
        __syncthreads();

        {   // scan 1: dst buckets
            int v = (tid < NB) ? l_cnt[tid] : 0;
            int inc = v;
            #pragma unroll
            for (int off = 1; off < 64; off <<= 1) {
                int t = __shfl_up(inc, off);
                if (lane >= off) inc += t;
            }
            if (lane == 63) wsum_s[wid] = inc;
            __syncthreads();
            int woff = 0;
            #pragma unroll
            for (int w = 0; w < 8; ++w) if (w < wid) woff += wsum_s[w];
            int excl = woff + inc - v;
            if (tid < NB) {
                l_base[tid] = excl;
                l_pos[tid]  = excl;
                g_base[tid] = v ? atomicAdd(&bucket_cnt[tid], v) : 0;
            }
        }
        __syncthreads();
        {   // scan 2: src buckets
            int v = (tid < NB) ? l_cnt2[tid] : 0;
            int inc = v;
            #pragma unroll
            for (int off = 1; off < 64; off <<= 1) {
                int t = __shfl_up(inc, off);
                if (lane >= off) inc += t;
            }
            if (lane == 63) wsum_s[wid] = inc;
            __syncthreads();
            int woff = 0;
            #pragma unroll
            for (int w = 0; w < 8; ++w) if (w < wid) woff += wsum_s[w];
            int excl = woff + inc - v;
            if (tid < NB) {
                l_base2[tid] = excl;
                l_pos2[tid]  = excl;
                g_base2[tid] = v ? atomicAdd(&bucket_cnt2[tid], v) : 0;
            }
        }
        __syncthreads();

        #pragma unroll
        for (int k = 0; k < 8; ++k) {
            if (r_bk[k] >= 0) {
                unsigned pk = r_pk[k];
                int p = atomicAdd(&l_pos[(int)r_bk[k]], 1);
                buf[p] = pk;
                bkt_of[p] = (unsigned short)r_bk[k];
                int bk2 = (int)((pk >> 8) & 0x1FF);
                int p2 = atomicAdd(&l_pos2[bk2], 1);
                bbuf[p2] = (unsigned char)(pk & 255);
                bkt2_of[p2] = (unsigned short)bk2;
            }
        }
        __syncthreads();

        for (int i = tid; i < cn; i += 512) {
            int bk = bkt_of[i];
            int gp = g_base[bk] + (i - l_base[bk]);
            if (gp < CAPB)
                pairs[(long)bk * CAPB + gp] = buf[i];
            int b2 = bkt2_of[i];
            int gp2 = g_base2[b2] + (i - l_base2[b2]);
            if (gp2 < CAPB)
                sbytes[(long)b2 * CAPB + gp2] = bbuf[i];
        }
    } else {
        // ---------------- gemm path (R0-identical loop, unscaled) ----------------
        float* Wl = (float*)smem;                  // 32768 B
        float* xl = (float*)(smem + 32768);        // 16384 B
        for (int i = tid; i < IN_F * OUT_F; i += 512) Wl[i] = W[i];

        const int sub = tid >> 6;
        const int col = tid & 63;

        for (int g = idx; g < G_GROUPS; g += G_BLOCKS) {
            __syncthreads();
            const float4* xg = (const float4*)(x + (long)g * G_TILE * IN_F);
            float4* xl4 = (float4*)xl;
            xl4[tid]       = xg[tid];
            xl4[tid + 512] = xg[tid + 512];
            __syncthreads();

            float a0 = 0.0f, a1 = 0.0f, a2 = 0.0f, a3 = 0.0f;
            const float* xr = xl + sub * 4 * IN_F;
            #pragma unroll
            for (int k4 = 0; k4 < IN_F / 4; ++k4) {
                float4 x0 = ((const float4*)xr)[k4];
                float4 x1 = ((const float4*)(xr + IN_F))[k4];
                float4 x2 = ((const float4*)(xr + 2 * IN_F))[k4];
                float4 x3 = ((const float4*)(xr + 3 * IN_F))[k4];
                float w0 = Wl[(k4 * 4 + 0) * OUT_F + col];
                float w1 = Wl[(k4 * 4 + 1) * OUT_F + col];
                float w2 = Wl[(k4 * 4 + 2) * OUT_F + col];
                float w3 = Wl[(k4 * 4 + 3) * OUT_F + col];
                a0 += x0.x * w0 + x0.y * w1 + x0.z * w2 + x0.w * w3;
                a1 += x1.x * w0 + x1.y * w1 + x1.z * w2 + x1.w * w3;
                a2 += x2.x * w0 + x2.y * w1 + x2.z * w2 + x2.w * w3;
                a3 += x3.x * w0 + x3.y * w1 + x3.z * w2 + x3.w * w3;
            }

            const int r0 = g * G_TILE + sub * 4;
            sxw[(long)(r0 + 0) * OUT_F + col] = __float2bfloat16(a0);
            sxw[(long)(r0 + 1) * OUT_F + col] = __float2bfloat16(a1);
            sxw[(long)(r0 + 2) * OUT_F + col] = __float2bfloat16(a2);
            sxw[(long)(r0 + 3) * OUT_F + col] = __float2bfloat16(a3);
        }
    }
}

// ---- Kernel 2 (cc): [0,NB) csr (register-resident) | [NB,2NB) count -> rsq ----
__global__ __launch_bounds__(512) void cc_kernel(
        unsigned* __restrict__ pairs, const int* __restrict__ bucket_cnt,
        const unsigned char* __restrict__ sbytes, const int* __restrict__ bucket_cnt2,
        int* __restrict__ row_beg, int* __restrict__ row_deg,
        float* __restrict__ rsq_out) {
    alignas(16) __shared__ char smem[4096];        // hist 1KB | cur 1KB | wsum
    const int tid = threadIdx.x;

    if (blockIdx.x < NB) {
        int* hist = (int*)smem;                    // 1024 B
        int* cur  = hist + 256;                    // 1024 B
        int* wsum = cur + 256;                     // 16 B
        const int lane = tid & 63;
        const int wid  = tid >> 6;
        const int bk   = blockIdx.x;
        const long base = (long)bk * CAPB;
        const int cnt  = min(bucket_cnt[bk], CAPB);
        const int n4   = cnt >> 2;                 // <= 2560
        const uint4* p4 = (const uint4*)(pairs + base);

        if (tid < 256) hist[tid] = 0;
        __syncthreads();

        unsigned ev[20];
        #pragma unroll
        for (int k = 0; k < 5; ++k) {
            const int i4 = tid + k * 512;
            if (i4 < n4) {
                uint4 q = p4[i4];
                ev[k * 4 + 0] = q.x; ev[k * 4 + 1] = q.y;
                ev[k * 4 + 2] = q.z; ev[k * 4 + 3] = q.w;
                atomicAdd(&hist[q.x >> 17], 1);
                atomicAdd(&hist[q.y >> 17], 1);
                atomicAdd(&hist[q.z >> 17], 1);
                atomicAdd(&hist[q.w >> 17], 1);
            } else {
                ev[k * 4 + 0] = 0xFFFFFFFFu; ev[k * 4 + 1] = 0xFFFFFFFFu;
                ev[k * 4 + 2] = 0xFFFFFFFFu; ev[k * 4 + 3] = 0xFFFFFFFFu;
            }
        }
        unsigned et = 0xFFFFFFFFu;
        if (tid < (cnt & 3)) {
            et = pairs[base + (n4 << 2) + tid];
            atomicAdd(&hist[et >> 17], 1);
        }
        __syncthreads();

        int v = (tid < 256) ? hist[tid] : 0;
        int inc = v;
        #pragma unroll
        for (int off = 1; off < 64; off <<= 1) {
            int t = __shfl_up(inc, off);
            if (lane >= off) inc += t;
        }
        if (tid < 256 && lane == 63) wsum[wid] = inc;
        __syncthreads();
        if (tid < 256) {
            int woff = 0;
            #pragma unroll
            for (int w = 0; w < 4; ++w) if (w < wid) woff += wsum[w];
            int excl = woff + inc - v;
            cur[tid] = excl;
            const int node = bk * BUCKET_NODES + tid;
            if (node < N_NODES) {
                row_beg[node] = (int)(base + excl);
                row_deg[node] = v;
            }
        }
        __syncthreads();

        #pragma unroll
        for (int k = 0; k < 20; ++k) {
            if (ev[k] != 0xFFFFFFFFu) {
                int p = atomicAdd(&cur[ev[k] >> 17], 1);
                pairs[base + p] = ev[k] & 0x1FFFF;
            }
        }
        if (et != 0xFFFFFFFFu) {
            int p = atomicAdd(&cur[et >> 17], 1);
            pairs[base + p] = et & 0x1FFFF;
        }
    } else {
        int* hist = (int*)smem;                    // 1024 B
        const int bk = blockIdx.x - NB;
        if (tid < 256) hist[tid] = 0;
        __syncthreads();

        const int cnt = min(bucket_cnt2[bk], CAPB);
        const unsigned* sb4 = (const unsigned*)(sbytes + (long)bk * CAPB);
        const int n4 = cnt >> 2;
        for (int i = tid; i < n4; i += 512) {
            unsigned u = sb4[i];
            atomicAdd(&hist[u & 255], 1);
            atomicAdd(&hist[(u >> 8) & 255], 1);
            atomicAdd(&hist[(u >> 16) & 255], 1);
            atomicAdd(&hist[u >> 24], 1);
        }
        for (int i = (n4 << 2) + tid; i < cnt; i += 512)
            atomicAdd(&hist[sbytes[(long)bk * CAPB + i]], 1);
        __syncthreads();

        if (tid < 256) {
            const int node = bk * BUCKET_NODES + tid;
            if (node < N_NODES) {
                int d = hist[tid];
                rsq_out[node] = rsqrtf((float)(d < 1 ? 1 : d));
            }
        }
    }
}

// ---- Kernel 3: gather, 2 nodes per wave, fused main loops (8 loads in flight) ----
#define ACCA(u, rs) {                                           \
    a0 = fmaf(__uint_as_float((u).x << 16),         (rs), a0);  \
    a1 = fmaf(__uint_as_float((u).x & 0xFFFF0000u), (rs), a1);  \
    a2 = fmaf(__uint_as_float((u).y << 16),         (rs), a2);  \
    a3 = fmaf(__uint_as_float((u).y & 0xFFFF0000u), (rs), a3);  \
    a4 = fmaf(__uint_as_float((u).z << 16),         (rs), a4);  \
    a5 = fmaf(__uint_as_float((u).z & 0xFFFF0000u), (rs), a5);  \
    a6 = fmaf(__uint_as_float((u).w << 16),         (rs), a6);  \
    a7 = fmaf(__uint_as_float((u).w & 0xFFFF0000u), (rs), a7);  \
}
#define ACCB(u, rs) {                                           \
    g0 = fmaf(__uint_as_float((u).x << 16),         (rs), g0);  \
    g1 = fmaf(__uint_as_float((u).x & 0xFFFF0000u), (rs), g1);  \
    g2 = fmaf(__uint_as_float((u).y << 16),         (rs), g2);  \
    g3 = fmaf(__uint_as_float((u).y & 0xFFFF0000u), (rs), g3);  \
    g4 = fmaf(__uint_as_float((u).z << 16),         (rs), g4);  \
    g5 = fmaf(__uint_as_float((u).z & 0xFFFF0000u), (rs), g5);  \
    g6 = fmaf(__uint_as_float((u).w << 16),         (rs), g6);  \
    g7 = fmaf(__uint_as_float((u).w & 0xFFFF0000u), (rs), g7);  \
}

__global__ __launch_bounds__(256) void gather_kernel(
        const int* __restrict__ row_beg, const int* __restrict__ row_deg,
        const unsigned* __restrict__ csr_src, const uint4* __restrict__ sxw4,
        const float* __restrict__ rsq_out,
        const float* __restrict__ b, float* __restrict__ out) {
    const int lane  = threadIdx.x & 63;
    const int wid   = threadIdx.x >> 6;          // 0..3
    const int nodeA = blockIdx.x * 8 + wid * 2;  // N_NODES % 8 == 0
    const int nodeB = nodeA + 1;

    const int eo = lane >> 3;     // edge slot 0..7
    const int c  = lane & 7;      // uint4 index within row (8 cols)

    const int begA = row_beg[nodeA], degA = row_deg[nodeA], endA = begA + degA;
    const int begB = row_beg[nodeB], degB = row_deg[nodeB], endB = begB + degB;

    float a0 = 0, a1 = 0, a2 = 0, a3 = 0, a4 = 0, a5 = 0, a6 = 0, a7 = 0;
    float g0 = 0, g1 = 0, g2 = 0, g3 = 0, g4 = 0, g5 = 0, g6 = 0, g7 = 0;

    int jA = begA, jB = begB;

    // fused main loops: both nodes active -> 8 independent row-gathers in flight
    while (jA + 32 <= endA && jB + 32 <= endB) {
        unsigned sA0 = csr_src[jA + eo];
        unsigned sA1 = csr_src[jA + 8 + eo];
        unsigned sA2 = csr_src[jA + 16 + eo];
        unsigned sA3 = csr_src[jA + 24 + eo];
        unsigned sB0 = csr_src[jB + eo];
        unsigned sB1 = csr_src[jB + 8 + eo];
        unsigned sB2 = csr_src[jB + 16 + eo];
        unsigned sB3 = csr_src[jB + 24 + eo];
        float rA0 = rsq_out[sA0], rA1 = rsq_out[sA1];
        float rA2 = rsq_out[sA2], rA3 = rsq_out[sA3];
        float rB0 = rsq_out[sB0], rB1 = rsq_out[sB1];
        float rB2 = rsq_out[sB2], rB3 = rsq_out[sB3];
        uint4 uA0 = sxw4[(long)sA0 * 8 + c];
        uint4 uA1 = sxw4[(long)sA1 * 8 + c];
        uint4 uA2 = sxw4[(long)sA2 * 8 + c];
        uint4 uA3 = sxw4[(long)sA3 * 8 + c];
        uint4 uB0 = sxw4[(long)sB0 * 8 + c];
        uint4 uB1 = sxw4[(long)sB1 * 8 + c];
        uint4 uB2 = sxw4[(long)sB2 * 8 + c];
        uint4 uB3 = sxw4[(long)sB3 * 8 + c];
        ACCA(uA0, rA0) ACCA(uA1, rA1) ACCA(uA2, rA2) ACCA(uA3, rA3)
        ACCB(uB0, rB0) ACCB(uB1, rB1) ACCB(uB2, rB2) ACCB(uB3, rB3)
        jA += 32; jB += 32;
    }
    // drain remaining 32-chunks (order per node identical to R20)
    for (; jA + 32 <= endA; jA += 32) {
        unsigned s0 = csr_src[jA + eo];
        unsigned s1 = csr_src[jA + 8 + eo];
        unsigned s2 = csr_src[jA + 16 + eo];
        unsigned s3 = csr_src[jA + 24 + eo];
        float r0 = rsq_out[s0], r1 = rsq_out[s1];
        float r2 = rsq_out[s2], r3 = rsq_out[s3];
        uint4 u0 = sxw4[(long)s0 * 8 + c];
        uint4 u1 = sxw4[(long)s1 * 8 + c];
        uint4 u2 = sxw4[(long)s2 * 8 + c];
        uint4 u3 = sxw4[(long)s3 * 8 + c];
        ACCA(u0, r0) ACCA(u1, r1) ACCA(u2, r2) ACCA(u3, r3)
    }
    for (; jB + 32 <= endB; jB += 32) {
        unsigned s0 = csr_src[jB + eo];
        unsigned s1 = csr_src[jB + 8 + eo];
        unsigned s2 = csr_src[jB + 16 + eo];
        unsigned s3 = csr_src[jB + 24 + eo];
        float r0 = rsq_out[s0], r1 = rsq_out[s1];
        float r2 = rsq_out[s2], r3 = rsq_out[s3];
        uint4 u0 = sxw4[(long)s0 * 8 + c];
        uint4 u1 = sxw4[(long)s1 * 8 + c];
        uint4 u2 = sxw4[(long)s2 * 8 + c];
        uint4 u3 = sxw4[(long)s3 * 8 + c];
        ACCB(u0, r0) ACCB(u1, r1) ACCB(u2, r2) ACCB(u3, r3)
    }
    // 8-step + tails, node A then node B (same per-node order as R20)
    for (; jA + 8 <= endA; jA += 8) {
        unsigned s = csr_src[jA + eo];
        float rs = rsq_out[s];
        uint4 u = sxw4[(long)s * 8 + c];
        ACCA(u, rs)
    }
    if (jA < endA) {
        int e = jA + eo;
        if (e < endA) {
            unsigned s = csr_src[e];
            float rs = rsq_out[s];
            uint4 u = sxw4[(long)s * 8 + c];
            ACCA(u, rs)
        }
    }
    for (; jB + 8 <= endB; jB += 8) {
        unsigned s = csr_src[jB + eo];
        float rs = rsq_out[s];
        uint4 u = sxw4[(long)s * 8 + c];
        ACCB(u, rs)
    }
    if (jB < endB) {
        int e = jB + eo;
        if (e < endB) {
            unsigned s = csr_src[e];
            float rs = rsq_out[s];
            uint4 u = sxw4[(long)s * 8 + c];
            ACCB(u, rs)
        }
    }

    #pragma unroll
    for (int off = 8; off < 64; off <<= 1) {
        a0 += __shfl_xor(a0, off);
        a1 += __shfl_xor(a1, off);
        a2 += __shfl_xor(a2, off);
        a3 += __shfl_xor(a3, off);
        a4 += __shfl_xor(a4, off);
        a5 += __shfl_xor(a5, off);
        a6 += __shfl_xor(a6, off);
        a7 += __shfl_xor(a7, off);
        g0 += __shfl_xor(g0, off);
        g1 += __shfl_xor(g1, off);
        g2 += __shfl_xor(g2, off);
        g3 += __shfl_xor(g3, off);
        g4 += __shfl_xor(g4, off);
        g5 += __shfl_xor(g5, off);
        g6 += __shfl_xor(g6, off);
        g7 += __shfl_xor(g7, off);
    }

    if (lane < 8) {
        float4 b0 = ((const float4*)b)[c * 2];
        float4 b1 = ((const float4*)b)[c * 2 + 1];
        {   // node A
            float d = (float)(degA < 1 ? 1 : degA);
            float s = rsqrtf(d);
            float4 o0, o1;
            o0.x = a0 * s + b0.x; o0.x = o0.x > 0.0f ? o0.x : 0.0f;
            o0.y = a1 * s + b0.y; o0.y = o0.y > 0.0f ? o0.y : 0.0f;
            o0.z = a2 * s + b0.z; o0.z = o0.z > 0.0f ? o0.z : 0.0f;
            o0.w = a3 * s + b0.w; o0.w = o0.w > 0.0f ? o0.w : 0.0f;
            o1.x = a4 * s + b1.x; o1.x = o1.x > 0.0f ? o1.x : 0.0f;
            o1.y = a5 * s + b1.y; o1.y = o1.y > 0.0f ? o1.y : 0.0f;
            o1.z = a6 * s + b1.z; o1.z = o1.z > 0.0f ? o1.z : 0.0f;
            o1.w = a7 * s + b1.w; o1.w = o1.w > 0.0f ? o1.w : 0.0f;
            float4* orow = (float4*)(out + (long)nodeA * OUT_F);
            orow[c * 2]     = o0;
            orow[c * 2 + 1] = o1;
        }
        {   // node B
            float d = (float)(degB < 1 ? 1 : degB);
            float s = rsqrtf(d);
            float4 o0, o1;
            o0.x = g0 * s + b0.x; o0.x = o0.x > 0.0f ? o0.x : 0.0f;
            o0.y = g1 * s + b0.y; o0.y = o0.y > 0.0f ? o0.y : 0.0f;
            o0.z = g2 * s + b0.z; o0.z = o0.z > 0.0f ? o0.z : 0.0f;
            o0.w = g3 * s + b0.w; o0.w = o0.w > 0.0f ? o0.w : 0.0f;
            o1.x = g4 * s + b1.x; o1.x = o1.x > 0.0f ? o1.x : 0.0f;
            o1.y = g5 * s + b1.y; o1.y = o1.y > 0.0f ? o1.y : 0.0f;
            o1.z = g6 * s + b1.z; o1.z = o1.z > 0.0f ? o1.z : 0.0f;
            o1.w = g7 * s + b1.w; o1.w = o1.w > 0.0f ? o1.w : 0.0f;
            float4* orow = (float4*)(out + (long)nodeB * OUT_F);
            orow[c * 2]     = o0;
            orow[c * 2 + 1] = o1;
        }
    }
}

extern "C" void kernel_launch(void* const* d_in, const int* in_sizes, int n_in,
                              void* d_out, int out_size, void* d_ws, size_t ws_size,
                              hipStream_t stream) {
    const float* in_feat = (const float*)d_in[0];
    const int*   src     = (const int*)d_in[1];
    const int*   dst     = (const int*)d_in[2];
    const float* W       = (const float*)d_in[3];
    const float* b       = (const float*)d_in[4];
    float*       out     = (float*)d_out;

    // ws: sxw bf16 [N*64] (12.8MB) | rsq_out [N] | bucket_cnt [NB] | bucket_cnt2 [NB]
    //   | row_beg [N] | row_deg [N] | pairs [NB*CAPB u32] (16MB) | sbytes [NB*CAPB] (4MB)
    __hip_bfloat16* sxw         = (__hip_bfloat16*)d_ws;
    float*          rsq_out     = (float*)(sxw + (size_t)N_NODES * OUT_F);
    int*            bucket_cnt  = (int*)(rsq_out + N_NODES);
    int*            bucket_cnt2 = bucket_cnt + NB;
    int*            row_beg     = bucket_cnt2 + NB;
    int*            row_deg     = row_beg + N_NODES;
    unsigned*       pairs       = (unsigned*)(row_deg + N_NODES);
    unsigned char*  sbytes      = (unsigned char*)(pairs + (size_t)NB * CAPB);

    hipMemsetAsync(bucket_cnt, 0, 2 * (size_t)NB * sizeof(int), stream);

    pg_kernel<<<PG_GRID, 512, 0, stream>>>(src, dst, bucket_cnt, bucket_cnt2,
                                           pairs, sbytes, in_feat, W, sxw);

    cc_kernel<<<2 * NB, 512, 0, stream>>>(pairs, bucket_cnt, sbytes, bucket_cnt2,
                                          row_beg, row_deg, rsq_out);

    gather_kernel<<<N_NODES / 8, 256, 0, stream>>>(row_beg, row_deg, pairs,
                                                   (const uint4*)sxw, rsq_out,
                                                   b, out);
}

// Round 11
// 245.593 us; speedup vs baseline: 1.1556x; 1.1556x over previous
//
#include <hip/hip_runtime.h>
#include <hip/hip_bf16.h>

// GCN GraphConv (norm='both', mult-first): out = relu( D_in^-1/2 * A * D_out^-1/2 * (X W) + b )
// N=100000 nodes, E=3200000 edges, IN=128, OUT=64, fp32 in/out.
//
// R22 = fuse csr-sort + gather into one per-half-bucket kernel (overlaps the
// DS-atomic-bound sort with the cache-BW-bound gather; deletes the 25.6MB
// sorted-pairs round trip and row_beg/row_deg):
//  K1 pg: INTERLEAVED partition | gemm — BYTE-IDENTICAL to R19/R20 (86us).
//  K2 count: standalone src-bucket hist -> rsq_out (R17-verified body, 391 blks).
//  K3 sg: block = half of a 256-node dst bucket (filter payload bit24, R12-
//     verified). Phase 1: coalesced pairs read + 128-bin LDS hist (own half).
//     Phase 2: scan -> begs/cur. Phase 3: re-read + scatter src into LDS
//     sorted[5632] (2 int atomics/edge total, same as cc). Phase 4: gather —
//     8-lane group per node (R15-verified), 4 edges in flight, VGPR accum,
//     fused rsqrt(deg_in)+bias+relu. No ev[] regs -> low VGPR, 4 blocks/CU.
// Lessons enforced: pg untouched (R17/R18: occupancy > micro-opts); no global
// per-edge atomics (R16); no LDS f32 accumulation (R12/13); gather stays
// TLP-hidden, no ILP over-engineering (R21).

constexpr int N_NODES = 100000;
constexpr int N_EDGES = 3200000;
constexpr int IN_F    = 128;
constexpr int OUT_F   = 64;
constexpr int BUCKET_NODES = 256;
constexpr int NB   = (N_NODES + BUCKET_NODES - 1) / BUCKET_NODES;  // 391
constexpr int CAPB = 10240;          // bucket capacity; mean 8184, sd~90 -> 22 sigma
constexpr int CAP_H = 5632;          // half-bucket capacity; mean 4092, sd~64 -> 24 sigma
constexpr int C_CHUNK  = 4096;
constexpr int C_BLOCKS = (N_EDGES + C_CHUNK - 1) / C_CHUNK;        // 782 (last cn=1024, %4==0)
constexpr int G_TILE   = 32;         // gemm rows per block-iteration
constexpr int G_BLOCKS = 1024;
constexpr int G_GROUPS = N_NODES / G_TILE;                         // 3125
constexpr int PG_GRID  = 2 * C_BLOCKS + (G_BLOCKS - C_BLOCKS);     // 1806

// ---- Kernel 1 (pg): interleaved partition | gemm (R19/R20-identical) ----
__global__ __launch_bounds__(512) void pg_kernel(
        const int* __restrict__ src, const int* __restrict__ dst,
        int* __restrict__ bucket_cnt, int* __restrict__ bucket_cnt2,
        unsigned* __restrict__ pairs, unsigned char* __restrict__ sbytes,
        const float* __restrict__ x, const float* __restrict__ W,
        __hip_bfloat16* __restrict__ sxw) {
    alignas(16) __shared__ char smem[49408];   // partition 49408 | gemm 49152
    const int tid = threadIdx.x;
    const int bid = blockIdx.x;

    bool is_part;
    int  idx;
    if (bid < 2 * C_BLOCKS) { is_part = (bid & 1) == 0; idx = bid >> 1; }
    else                    { is_part = false; idx = C_BLOCKS + (bid - 2 * C_BLOCKS); }

    if (is_part) {
        // ---------------- partition path (R0-identical body) ----------------
        int* l_cnt   = (int*)smem;
        int* l_base  = l_cnt   + NB;
        int* l_pos   = l_base  + NB;
        int* g_base  = l_pos   + NB;
        int* l_cnt2  = g_base  + NB;
        int* l_base2 = l_cnt2  + NB;
        int* l_pos2  = l_base2 + NB;
        int* g_base2 = l_pos2  + NB;                         // ends @12512
        int* wsum_s  = g_base2 + NB;                         // 32 B @12512
        unsigned*       buf     = (unsigned*)(smem + 12544);       // 16384 B
        unsigned short* bkt_of  = (unsigned short*)(smem + 28928); // 8192 B
        unsigned char*  bbuf    = (unsigned char*)(smem + 37120);  // 4096 B
        unsigned short* bkt2_of = (unsigned short*)(smem + 41216); // 8192 B

        const int lane = tid & 63;
        const int wid  = tid >> 6;
        const long e0 = (long)idx * C_CHUNK;
        const int  cn = (int)min((long)C_CHUNK, (long)N_EDGES - e0);
        const int  cn4 = cn >> 2;

        for (int i = tid; i < NB; i += 512) { l_cnt[i] = 0; l_cnt2[i] = 0; }
        __syncthreads();

        unsigned r_pk[8];
        short    r_bk[8];
        const int4* d4p = (const int4*)(dst + e0);
        const int4* s4p = (const int4*)(src + e0);
        #pragma unroll
        for (int k = 0; k < 2; ++k) {
            int i4 = tid + k * 512;
            int rb = k * 4;
            if (i4 < cn4) {
                int4 d4 = d4p[i4];
                int4 s4 = s4p[i4];
                int dd[4] = {d4.x, d4.y, d4.z, d4.w};
                int ss[4] = {s4.x, s4.y, s4.z, s4.w};
                #pragma unroll
                for (int j = 0; j < 4; ++j) {
                    int bk = dd[j] >> 8;
                    r_bk[rb + j] = (short)bk;
                    r_pk[rb + j] = ((unsigned)(dd[j] & 255) << 17) | (unsigned)ss[j];
                    atomicAdd(&l_cnt[bk], 1);
                    atomicAdd(&l_cnt2[ss[j] >> 8], 1);
                }
            } else {
                #pragma unroll
                for (int j = 0; j < 4; ++j) r_bk[rb + j] = -1;
            }
        }
        __syncthreads();

        {   // scan 1: dst buckets
            int v = (tid < NB) ? l_cnt[tid] : 0;
            int inc = v;
            #pragma unroll
            for (int off = 1; off < 64; off <<= 1) {
                int t = __shfl_up(inc, off);
                if (lane >= off) inc += t;
            }
            if (lane == 63) wsum_s[wid] = inc;
            __syncthreads();
            int woff = 0;
            #pragma unroll
            for (int w = 0; w < 8; ++w) if (w < wid) woff += wsum_s[w];
            int excl = woff + inc - v;
            if (tid < NB) {
                l_base[tid] = excl;
                l_pos[tid]  = excl;
                g_base[tid] = v ? atomicAdd(&bucket_cnt[tid], v) : 0;
            }
        }
        __syncthreads();
        {   // scan 2: src buckets
            int v = (tid < NB) ? l_cnt2[tid] : 0;
            int inc = v;
            #pragma unroll
            for (int off = 1; off < 64; off <<= 1) {
                int t = __shfl_up(inc, off);
                if (lane >= off) inc += t;
            }
            if (lane == 63) wsum_s[wid] = inc;
            __syncthreads();
            int woff = 0;
            #pragma unroll
            for (int w = 0; w < 8; ++w) if (w < wid) woff += wsum_s[w];
            int excl = woff + inc - v;
            if (tid < NB) {
                l_base2[tid] = excl;
                l_pos2[tid]  = excl;
                g_base2[tid] = v ? atomicAdd(&bucket_cnt2[tid], v) : 0;
            }
        }
        __syncthreads();

        #pragma unroll
        for (int k = 0; k < 8; ++k) {
            if (r_bk[k] >= 0) {
                unsigned pk = r_pk[k];
                int p = atomicAdd(&l_pos[(int)r_bk[k]], 1);
                buf[p] = pk;
                bkt_of[p] = (unsigned short)r_bk[k];
                int bk2 = (int)((pk >> 8) & 0x1FF);
                int p2 = atomicAdd(&l_pos2[bk2], 1);
                bbuf[p2] = (unsigned char)(pk & 255);
                bkt2_of[p2] = (unsigned short)bk2;
            }
        }
        __syncthreads();

        for (int i = tid; i < cn; i += 512) {
            int bk = bkt_of[i];
            int gp = g_base[bk] + (i - l_base[bk]);
            if (gp < CAPB)
                pairs[(long)bk * CAPB + gp] = buf[i];
            int b2 = bkt2_of[i];
            int gp2 = g_base2[b2] + (i - l_base2[b2]);
            if (gp2 < CAPB)
                sbytes[(long)b2 * CAPB + gp2] = bbuf[i];
        }
    } else {
        // ---------------- gemm path (R0-identical loop, unscaled) ----------------
        float* Wl = (float*)smem;                  // 32768 B
        float* xl = (float*)(smem + 32768);        // 16384 B
        for (int i = tid; i < IN_F * OUT_F; i += 512) Wl[i] = W[i];

        const int sub = tid >> 6;
        const int col = tid & 63;

        for (int g = idx; g < G_GROUPS; g += G_BLOCKS) {
            __syncthreads();
            const float4* xg = (const float4*)(x + (long)g * G_TILE * IN_F);
            float4* xl4 = (float4*)xl;
            xl4[tid]       = xg[tid];
            xl4[tid + 512] = xg[tid + 512];
            __syncthreads();

            float a0 = 0.0f, a1 = 0.0f, a2 = 0.0f, a3 = 0.0f;
            const float* xr = xl + sub * 4 * IN_F;
            #pragma unroll
            for (int k4 = 0; k4 < IN_F / 4; ++k4) {
                float4 x0 = ((const float4*)xr)[k4];
                float4 x1 = ((const float4*)(xr + IN_F))[k4];
                float4 x2 = ((const float4*)(xr + 2 * IN_F))[k4];
                float4 x3 = ((const float4*)(xr + 3 * IN_F))[k4];
                float w0 = Wl[(k4 * 4 + 0) * OUT_F + col];
                float w1 = Wl[(k4 * 4 + 1) * OUT_F + col];
                float w2 = Wl[(k4 * 4 + 2) * OUT_F + col];
                float w3 = Wl[(k4 * 4 + 3) * OUT_F + col];
                a0 += x0.x * w0 + x0.y * w1 + x0.z * w2 + x0.w * w3;
                a1 += x1.x * w0 + x1.y * w1 + x1.z * w2 + x1.w * w3;
                a2 += x2.x * w0 + x2.y * w1 + x2.z * w2 + x2.w * w3;
                a3 += x3.x * w0 + x3.y * w1 + x3.z * w2 + x3.w * w3;
            }

            const int r0 = g * G_TILE + sub * 4;
            sxw[(long)(r0 + 0) * OUT_F + col] = __float2bfloat16(a0);
            sxw[(long)(r0 + 1) * OUT_F + col] = __float2bfloat16(a1);
            sxw[(long)(r0 + 2) * OUT_F + col] = __float2bfloat16(a2);
            sxw[(long)(r0 + 3) * OUT_F + col] = __float2bfloat16(a3);
        }
    }
}

// ---- Kernel 2: count src-bucket histogram -> rsq_out (R17 body, standalone) ----
__global__ __launch_bounds__(512) void count_kernel(
        const unsigned char* __restrict__ sbytes, const int* __restrict__ bucket_cnt2,
        float* __restrict__ rsq_out) {
    __shared__ int hist[BUCKET_NODES];
    const int tid = threadIdx.x;
    const int bk  = blockIdx.x;
    if (tid < 256) hist[tid] = 0;
    __syncthreads();

    const int cnt = min(bucket_cnt2[bk], CAPB);
    const unsigned* sb4 = (const unsigned*)(sbytes + (long)bk * CAPB);
    const int n4 = cnt >> 2;
    for (int i = tid; i < n4; i += 512) {
        unsigned u = sb4[i];
        atomicAdd(&hist[u & 255], 1);
        atomicAdd(&hist[(u >> 8) & 255], 1);
        atomicAdd(&hist[(u >> 16) & 255], 1);
        atomicAdd(&hist[u >> 24], 1);
    }
    for (int i = (n4 << 2) + tid; i < cnt; i += 512)
        atomicAdd(&hist[sbytes[(long)bk * CAPB + i]], 1);
    __syncthreads();

    if (tid < 256) {
        const int node = bk * BUCKET_NODES + tid;
        if (node < N_NODES) {
            int d = hist[tid];
            rsq_out[node] = rsqrtf((float)(d < 1 ? 1 : d));
        }
    }
}

// ---- Kernel 3 (sg): per-half-bucket in-LDS sort + group-per-node gather ----
#define ACCG(u, rs) {                                           \
    a0 = fmaf(__uint_as_float((u).x << 16),         (rs), a0);  \
    a1 = fmaf(__uint_as_float((u).x & 0xFFFF0000u), (rs), a1);  \
    a2 = fmaf(__uint_as_float((u).y << 16),         (rs), a2);  \
    a3 = fmaf(__uint_as_float((u).y & 0xFFFF0000u), (rs), a3);  \
    a4 = fmaf(__uint_as_float((u).z << 16),         (rs), a4);  \
    a5 = fmaf(__uint_as_float((u).z & 0xFFFF0000u), (rs), a5);  \
    a6 = fmaf(__uint_as_float((u).w << 16),         (rs), a6);  \
    a7 = fmaf(__uint_as_float((u).w & 0xFFFF0000u), (rs), a7);  \
}

__global__ __launch_bounds__(512) void sg_kernel(
        const unsigned* __restrict__ pairs, const int* __restrict__ bucket_cnt,
        const float* __restrict__ rsq_out, const uint4* __restrict__ sxw4,
        const float* __restrict__ b, float* __restrict__ out) {
    __shared__ unsigned sorted[CAP_H];         // 22528 B (src ids, dl-sorted)
    __shared__ int hist[128];
    __shared__ int cur[128];
    __shared__ int begs[129];
    __shared__ int wsum[2];
    const int tid  = threadIdx.x;
    const int bk   = blockIdx.x >> 1;          // 256-node dst bucket
    const unsigned h = blockIdx.x & 1;         // half (payload bit 24)
    const int lane = tid & 63;
    const int wid  = tid >> 6;

    if (tid < 128) hist[tid] = 0;
    __syncthreads();

    const long base = (long)bk * CAPB;
    const int  cnt  = min(bucket_cnt[bk], CAPB);
    const int  n4   = cnt >> 2;
    const uint4* p4 = (const uint4*)(pairs + base);

    // phase 1: histogram own-half dst-locals (coalesced read, 1 atomic/own edge)
    for (int i4 = tid; i4 < n4; i4 += 512) {
        uint4 q = p4[i4];
        if (((q.x >> 24) & 1u) == h) atomicAdd(&hist[(q.x >> 17) & 127], 1);
        if (((q.y >> 24) & 1u) == h) atomicAdd(&hist[(q.y >> 17) & 127], 1);
        if (((q.z >> 24) & 1u) == h) atomicAdd(&hist[(q.z >> 17) & 127], 1);
        if (((q.w >> 24) & 1u) == h) atomicAdd(&hist[(q.w >> 17) & 127], 1);
    }
    for (int i = (n4 << 2) + tid; i < cnt; i += 512) {
        unsigned e = pairs[base + i];
        if (((e >> 24) & 1u) == h) atomicAdd(&hist[(e >> 17) & 127], 1);
    }
    __syncthreads();

    // phase 2: exclusive scan of 128 bins (2 waves)
    {
        int v = (tid < 128) ? hist[tid] : 0;
        int inc = v;
        #pragma unroll
        for (int off = 1; off < 64; off <<= 1) {
            int t = __shfl_up(inc, off);
            if (lane >= off) inc += t;
        }
        if (tid < 128 && lane == 63) wsum[wid] = inc;
        __syncthreads();
        if (tid < 128) {
            int excl = inc - v + (wid ? wsum[0] : 0);
            begs[tid] = excl;
            cur[tid]  = excl;
            if (tid == 127) begs[128] = excl + v;
        }
        __syncthreads();
    }

    // phase 3: re-read (L2-hot) + scatter own-half src into sorted LDS
    for (int i4 = tid; i4 < n4; i4 += 512) {
        uint4 q = p4[i4];
        unsigned w4[4] = {q.x, q.y, q.z, q.w};
        #pragma unroll
        for (int j = 0; j < 4; ++j) {
            unsigned e = w4[j];
            if (((e >> 24) & 1u) == h) {
                int p = atomicAdd(&cur[(e >> 17) & 127], 1);
                if (p < CAP_H) sorted[p] = e & 0x1FFFFu;
            }
        }
    }
    for (int i = (n4 << 2) + tid; i < cnt; i += 512) {
        unsigned e = pairs[base + i];
        if (((e >> 24) & 1u) == h) {
            int p = atomicAdd(&cur[(e >> 17) & 127], 1);
            if (p < CAP_H) sorted[p] = e & 0x1FFFFu;
        }
    }
    __syncthreads();

    // phase 4: gather — 8-lane group per node, 2 nodes per group (R15 pattern)
    const int grp = tid >> 3;                  // 0..63
    const int c   = tid & 7;                   // uint4 col 0..7
    const float4 b0 = ((const float4*)b)[c * 2];
    const float4 b1 = ((const float4*)b)[c * 2 + 1];
    const int node0 = bk * BUCKET_NODES + (int)h * 128;

    #pragma unroll
    for (int half = 0; half < 2; ++half) {
        const int n    = grp + half * 64;
        const int node = node0 + n;
        if (node < N_NODES) {
            int jb = begs[n], je = begs[n + 1];
            const int dg = je - jb;            // true in-degree
            if (je > CAP_H) je = CAP_H;
            if (jb > je) jb = je;
            float a0 = 0, a1 = 0, a2 = 0, a3 = 0, a4 = 0, a5 = 0, a6 = 0, a7 = 0;
            int j = jb;
            for (; j + 4 <= je; j += 4) {      // 4 edges in flight
                int s0 = (int)sorted[j];
                int s1 = (int)sorted[j + 1];
                int s2 = (int)sorted[j + 2];
                int s3 = (int)sorted[j + 3];
                float r0 = rsq_out[s0], r1 = rsq_out[s1];
                float r2 = rsq_out[s2], r3 = rsq_out[s3];
                uint4 u0 = sxw4[(long)s0 * 8 + c];
                uint4 u1 = sxw4[(long)s1 * 8 + c];
                uint4 u2 = sxw4[(long)s2 * 8 + c];
                uint4 u3 = sxw4[(long)s3 * 8 + c];
                ACCG(u0, r0) ACCG(u1, r1) ACCG(u2, r2) ACCG(u3, r3)
            }
            for (; j < je; ++j) {
                int s = (int)sorted[j];
                float rs = rsq_out[s];
                uint4 u = sxw4[(long)s * 8 + c];
                ACCG(u, rs)
            }
            float s = rsqrtf((float)(dg < 1 ? 1 : dg));
            float4 o0, o1;
            o0.x = fmaxf(fmaf(a0, s, b0.x), 0.0f);
            o0.y = fmaxf(fmaf(a1, s, b0.y), 0.0f);
            o0.z = fmaxf(fmaf(a2, s, b0.z), 0.0f);
            o0.w = fmaxf(fmaf(a3, s, b0.w), 0.0f);
            o1.x = fmaxf(fmaf(a4, s, b1.x), 0.0f);
            o1.y = fmaxf(fmaf(a5, s, b1.y), 0.0f);
            o1.z = fmaxf(fmaf(a6, s, b1.z), 0.0f);
            o1.w = fmaxf(fmaf(a7, s, b1.w), 0.0f);
            float4* orow = (float4*)(out + (long)node * OUT_F);
            orow[c * 2]     = o0;
            orow[c * 2 + 1] = o1;
        }
    }
}

extern "C" void kernel_launch(void* const* d_in, const int* in_sizes, int n_in,
                              void* d_out, int out_size, void* d_ws, size_t ws_size,
                              hipStream_t stream) {
    const float* in_feat = (const float*)d_in[0];
    const int*   src     = (const int*)d_in[1];
    const int*   dst     = (const int*)d_in[2];
    const float* W       = (const float*)d_in[3];
    const float* b       = (const float*)d_in[4];
    float*       out     = (float*)d_out;

    // ws: sxw bf16 [N*64] (12.8MB) | rsq_out [N] | bucket_cnt [NB] | bucket_cnt2 [NB]
    //   | pairs [NB*CAPB u32] (16MB) | sbytes [NB*CAPB] (4MB)
    __hip_bfloat16* sxw         = (__hip_bfloat16*)d_ws;
    float*          rsq_out     = (float*)(sxw + (size_t)N_NODES * OUT_F);
    int*            bucket_cnt  = (int*)(rsq_out + N_NODES);
    int*            bucket_cnt2 = bucket_cnt + NB;
    unsigned*       pairs       = (unsigned*)(bucket_cnt2 + NB + 2);  // 16B-align pad
    unsigned char*  sbytes      = (unsigned char*)(pairs + (size_t)NB * CAPB);

    hipMemsetAsync(bucket_cnt, 0, 2 * (size_t)NB * sizeof(int), stream);

    pg_kernel<<<PG_GRID, 512, 0, stream>>>(src, dst, bucket_cnt, bucket_cnt2,
                                           pairs, sbytes, in_feat, W, sxw);

    count_kernel<<<NB, 512, 0, stream>>>(sbytes, bucket_cnt2, rsq_out);

    sg_kernel<<<2 * NB, 512, 0, stream>>>(pairs, bucket_cnt, rsq_out,
                                          (const uint4*)sxw, b, out);
}

// Round 12
// 242.781 us; speedup vs baseline: 1.1690x; 1.0116x over previous
//
#include <hip/hip_runtime.h>
#include <hip/hip_bf16.h>

// GCN GraphConv (norm='both', mult-first): out = relu( D_in^-1/2 * A * D_out^-1/2 * (X W) + b )
// N=100000 nodes, E=3200000 edges, IN=128, OUT=64, fp32 in/out.
//
// R23 = R22 with sg's sort phases register-staged (R20-verified transform):
//  K1 pg: INTERLEAVED partition | gemm — BYTE-IDENTICAL to R19/R20/R22 (86us).
//  K2 count: src-bucket hist -> rsq_out (R22-identical).
//  K3 sg: per half-bucket: ONE coalesced pass over pairs -> ev[20] regs
//     (own-half only, sentinel 0xFFFFFFFF; max payload 0x1FFFFFF so safe),
//     hist from regs -> scan -> scatter from regs -> gather (R22-identical
//     phase 4: 8-lane group per node, 4 edges in flight, VGPR accum).
//     Deletes the second 16MB pairs read + second filter pass.
// Lessons enforced: pg untouched; no global per-edge atomics (R16); no LDS
// f32 accumulation (R12/13); gather TLP-hidden, no ILP over-eng (R21).

constexpr int N_NODES = 100000;
constexpr int N_EDGES = 3200000;
constexpr int IN_F    = 128;
constexpr int OUT_F   = 64;
constexpr int BUCKET_NODES = 256;
constexpr int NB   = (N_NODES + BUCKET_NODES - 1) / BUCKET_NODES;  // 391
constexpr int CAPB = 10240;          // bucket capacity; mean 8184, sd~90 -> 22 sigma
constexpr int CAP_H = 5632;          // half-bucket capacity; mean 4092, sd~64 -> 24 sigma
constexpr int C_CHUNK  = 4096;
constexpr int C_BLOCKS = (N_EDGES + C_CHUNK - 1) / C_CHUNK;        // 782 (last cn=1024, %4==0)
constexpr int G_TILE   = 32;         // gemm rows per block-iteration
constexpr int G_BLOCKS = 1024;
constexpr int G_GROUPS = N_NODES / G_TILE;                         // 3125
constexpr int PG_GRID  = 2 * C_BLOCKS + (G_BLOCKS - C_BLOCKS);     // 1806

// ---- Kernel 1 (pg): interleaved partition | gemm (R19/R20/R22-identical) ----
__global__ __launch_bounds__(512) void pg_kernel(
        const int* __restrict__ src, const int* __restrict__ dst,
        int* __restrict__ bucket_cnt, int* __restrict__ bucket_cnt2,
        unsigned* __restrict__ pairs, unsigned char* __restrict__ sbytes,
        const float* __restrict__ x, const float* __restrict__ W,
        __hip_bfloat16* __restrict__ sxw) {
    alignas(16) __shared__ char smem[49408];   // partition 49408 | gemm 49152
    const int tid = threadIdx.x;
    const int bid = blockIdx.x;

    bool is_part;
    int  idx;
    if (bid < 2 * C_BLOCKS) { is_part = (bid & 1) == 0; idx = bid >> 1; }
    else                    { is_part = false; idx = C_BLOCKS + (bid - 2 * C_BLOCKS); }

    if (is_part) {
        // ---------------- partition path (R0-identical body) ----------------
        int* l_cnt   = (int*)smem;
        int* l_base  = l_cnt   + NB;
        int* l_pos   = l_base  + NB;
        int* g_base  = l_pos   + NB;
        int* l_cnt2  = g_base  + NB;
        int* l_base2 = l_cnt2  + NB;
        int* l_pos2  = l_base2 + NB;
        int* g_base2 = l_pos2  + NB;                         // ends @12512
        int* wsum_s  = g_base2 + NB;                         // 32 B @12512
        unsigned*       buf     = (unsigned*)(smem + 12544);       // 16384 B
        unsigned short* bkt_of  = (unsigned short*)(smem + 28928); // 8192 B
        unsigned char*  bbuf    = (unsigned char*)(smem + 37120);  // 4096 B
        unsigned short* bkt2_of = (unsigned short*)(smem + 41216); // 8192 B

        const int lane = tid & 63;
        const int wid  = tid >> 6;
        const long e0 = (long)idx * C_CHUNK;
        const int  cn = (int)min((long)C_CHUNK, (long)N_EDGES - e0);
        const int  cn4 = cn >> 2;

        for (int i = tid; i < NB; i += 512) { l_cnt[i] = 0; l_cnt2[i] = 0; }
        __syncthreads();

        unsigned r_pk[8];
        short    r_bk[8];
        const int4* d4p = (const int4*)(dst + e0);
        const int4* s4p = (const int4*)(src + e0);
        #pragma unroll
        for (int k = 0; k < 2; ++k) {
            int i4 = tid + k * 512;
            int rb = k * 4;
            if (i4 < cn4) {
                int4 d4 = d4p[i4];
                int4 s4 = s4p[i4];
                int dd[4] = {d4.x, d4.y, d4.z, d4.w};
                int ss[4] = {s4.x, s4.y, s4.z, s4.w};
                #pragma unroll
                for (int j = 0; j < 4; ++j) {
                    int bk = dd[j] >> 8;
                    r_bk[rb + j] = (short)bk;
                    r_pk[rb + j] = ((unsigned)(dd[j] & 255) << 17) | (unsigned)ss[j];
                    atomicAdd(&l_cnt[bk], 1);
                    atomicAdd(&l_cnt2[ss[j] >> 8], 1);
                }
            } else {
                #pragma unroll
                for (int j = 0; j < 4; ++j) r_bk[rb + j] = -1;
            }
        }
        __syncthreads();

        {   // scan 1: dst buckets
            int v = (tid < NB) ? l_cnt[tid] : 0;
            int inc = v;
            #pragma unroll
            for (int off = 1; off < 64; off <<= 1) {
                int t = __shfl_up(inc, off);
                if (lane >= off) inc += t;
            }
            if (lane == 63) wsum_s[wid] = inc;
            __syncthreads();
            int woff = 0;
            #pragma unroll
            for (int w = 0; w < 8; ++w) if (w < wid) woff += wsum_s[w];
            int excl = woff + inc - v;
            if (tid < NB) {
                l_base[tid] = excl;
                l_pos[tid]  = excl;
                g_base[tid] = v ? atomicAdd(&bucket_cnt[tid], v) : 0;
            }
        }
        __syncthreads();
        {   // scan 2: src buckets
            int v = (tid < NB) ? l_cnt2[tid] : 0;
            int inc = v;
            #pragma unroll
            for (int off = 1; off < 64; off <<= 1) {
                int t = __shfl_up(inc, off);
                if (lane >= off) inc += t;
            }
            if (lane == 63) wsum_s[wid] = inc;
            __syncthreads();
            int woff = 0;
            #pragma unroll
            for (int w = 0; w < 8; ++w) if (w < wid) woff += wsum_s[w];
            int excl = woff + inc - v;
            if (tid < NB) {
                l_base2[tid] = excl;
                l_pos2[tid]  = excl;
                g_base2[tid] = v ? atomicAdd(&bucket_cnt2[tid], v) : 0;
            }
        }
        __syncthreads();

        #pragma unroll
        for (int k = 0; k < 8; ++k) {
            if (r_bk[k] >= 0) {
                unsigned pk = r_pk[k];
                int p = atomicAdd(&l_pos[(int)r_bk[k]], 1);
                buf[p] = pk;
                bkt_of[p] = (unsigned short)r_bk[k];
                int bk2 = (int)((pk >> 8) & 0x1FF);
                int p2 = atomicAdd(&l_pos2[bk2], 1);
                bbuf[p2] = (unsigned char)(pk & 255);
                bkt2_of[p2] = (unsigned short)bk2;
            }
        }
        __syncthreads();

        for (int i = tid; i < cn; i += 512) {
            int bk = bkt_of[i];
            int gp = g_base[bk] + (i - l_base[bk]);
            if (gp < CAPB)
                pairs[(long)bk * CAPB + gp] = buf[i];
            int b2 = bkt2_of[i];
            int gp2 = g_base2[b2] + (i - l_base2[b2]);
            if (gp2 < CAPB)
                sbytes[(long)b2 * CAPB + gp2] = bbuf[i];
        }
    } else {
        // ---------------- gemm path (R0-identical loop, unscaled) ----------------
        float* Wl = (float*)smem;                  // 32768 B
        float* xl = (float*)(smem + 32768);        // 16384 B
        for (int i = tid; i < IN_F * OUT_F; i += 512) Wl[i] = W[i];

        const int sub = tid >> 6;
        const int col = tid & 63;

        for (int g = idx; g < G_GROUPS; g += G_BLOCKS) {
            __syncthreads();
            const float4* xg = (const float4*)(x + (long)g * G_TILE * IN_F);
            float4* xl4 = (float4*)xl;
            xl4[tid]       = xg[tid];
            xl4[tid + 512] = xg[tid + 512];
            __syncthreads();

            float a0 = 0.0f, a1 = 0.0f, a2 = 0.0f, a3 = 0.0f;
            const float* xr = xl + sub * 4 * IN_F;
            #pragma unroll
            for (int k4 = 0; k4 < IN_F / 4; ++k4) {
                float4 x0 = ((const float4*)xr)[k4];
                float4 x1 = ((const float4*)(xr + IN_F))[k4];
                float4 x2 = ((const float4*)(xr + 2 * IN_F))[k4];
                float4 x3 = ((const float4*)(xr + 3 * IN_F))[k4];
                float w0 = Wl[(k4 * 4 + 0) * OUT_F + col];
                float w1 = Wl[(k4 * 4 + 1) * OUT_F + col];
                float w2 = Wl[(k4 * 4 + 2) * OUT_F + col];
                float w3 = Wl[(k4 * 4 + 3) * OUT_F + col];
                a0 += x0.x * w0 + x0.y * w1 + x0.z * w2 + x0.w * w3;
                a1 += x1.x * w0 + x1.y * w1 + x1.z * w2 + x1.w * w3;
                a2 += x2.x * w0 + x2.y * w1 + x2.z * w2 + x2.w * w3;
                a3 += x3.x * w0 + x3.y * w1 + x3.z * w2 + x3.w * w3;
            }

            const int r0 = g * G_TILE + sub * 4;
            sxw[(long)(r0 + 0) * OUT_F + col] = __float2bfloat16(a0);
            sxw[(long)(r0 + 1) * OUT_F + col] = __float2bfloat16(a1);
            sxw[(long)(r0 + 2) * OUT_F + col] = __float2bfloat16(a2);
            sxw[(long)(r0 + 3) * OUT_F + col] = __float2bfloat16(a3);
        }
    }
}

// ---- Kernel 2: count src-bucket histogram -> rsq_out (R22-identical) ----
__global__ __launch_bounds__(512) void count_kernel(
        const unsigned char* __restrict__ sbytes, const int* __restrict__ bucket_cnt2,
        float* __restrict__ rsq_out) {
    __shared__ int hist[BUCKET_NODES];
    const int tid = threadIdx.x;
    const int bk  = blockIdx.x;
    if (tid < 256) hist[tid] = 0;
    __syncthreads();

    const int cnt = min(bucket_cnt2[bk], CAPB);
    const unsigned* sb4 = (const unsigned*)(sbytes + (long)bk * CAPB);
    const int n4 = cnt >> 2;
    for (int i = tid; i < n4; i += 512) {
        unsigned u = sb4[i];
        atomicAdd(&hist[u & 255], 1);
        atomicAdd(&hist[(u >> 8) & 255], 1);
        atomicAdd(&hist[(u >> 16) & 255], 1);
        atomicAdd(&hist[u >> 24], 1);
    }
    for (int i = (n4 << 2) + tid; i < cnt; i += 512)
        atomicAdd(&hist[sbytes[(long)bk * CAPB + i]], 1);
    __syncthreads();

    if (tid < 256) {
        const int node = bk * BUCKET_NODES + tid;
        if (node < N_NODES) {
            int d = hist[tid];
            rsq_out[node] = rsqrtf((float)(d < 1 ? 1 : d));
        }
    }
}

// ---- Kernel 3 (sg): reg-staged half-bucket sort + group-per-node gather ----
#define ACCG(u, rs) {                                           \
    a0 = fmaf(__uint_as_float((u).x << 16),         (rs), a0);  \
    a1 = fmaf(__uint_as_float((u).x & 0xFFFF0000u), (rs), a1);  \
    a2 = fmaf(__uint_as_float((u).y << 16),         (rs), a2);  \
    a3 = fmaf(__uint_as_float((u).y & 0xFFFF0000u), (rs), a3);  \
    a4 = fmaf(__uint_as_float((u).z << 16),         (rs), a4);  \
    a5 = fmaf(__uint_as_float((u).z & 0xFFFF0000u), (rs), a5);  \
    a6 = fmaf(__uint_as_float((u).w << 16),         (rs), a6);  \
    a7 = fmaf(__uint_as_float((u).w & 0xFFFF0000u), (rs), a7);  \
}

__global__ __launch_bounds__(512) void sg_kernel(
        const unsigned* __restrict__ pairs, const int* __restrict__ bucket_cnt,
        const float* __restrict__ rsq_out, const uint4* __restrict__ sxw4,
        const float* __restrict__ b, float* __restrict__ out) {
    __shared__ unsigned sorted[CAP_H];         // 22528 B (src ids, dl-sorted)
    __shared__ int hist[128];
    __shared__ int cur[128];
    __shared__ int begs[129];
    __shared__ int wsum[2];
    const int tid  = threadIdx.x;
    const int bk   = blockIdx.x >> 1;          // 256-node dst bucket
    const unsigned h = blockIdx.x & 1;         // half (payload bit 24 = dl>=128)
    const int lane = tid & 63;
    const int wid  = tid >> 6;

    if (tid < 128) hist[tid] = 0;
    __syncthreads();

    const long base = (long)bk * CAPB;
    const int  cnt  = min(bucket_cnt[bk], CAPB);
    const int  n4   = cnt >> 2;                // <= 2560
    const uint4* p4 = (const uint4*)(pairs + base);

    // phase 1: ONE coalesced pass -> regs (own half only) + LDS hist
    // sentinel 0xFFFFFFFF is safe: max payload = (255<<17)|0x1FFFF = 0x1FFFFFF
    unsigned ev[20];
    #pragma unroll
    for (int k = 0; k < 5; ++k) {
        const int i4 = tid + k * 512;
        if (i4 < n4) {
            uint4 q = p4[i4];
            unsigned w4[4] = {q.x, q.y, q.z, q.w};
            #pragma unroll
            for (int j = 0; j < 4; ++j) {
                if (((w4[j] >> 24) & 1u) == h) {
                    ev[k * 4 + j] = w4[j];
                    atomicAdd(&hist[(w4[j] >> 17) & 127], 1);
                } else {
                    ev[k * 4 + j] = 0xFFFFFFFFu;
                }
            }
        } else {
            #pragma unroll
            for (int j = 0; j < 4; ++j) ev[k * 4 + j] = 0xFFFFFFFFu;
        }
    }
    unsigned et = 0xFFFFFFFFu;                 // tail (cnt & 3 edges)
    if (tid < (cnt & 3)) {
        unsigned e = pairs[base + (n4 << 2) + tid];
        if (((e >> 24) & 1u) == h) {
            et = e;
            atomicAdd(&hist[(e >> 17) & 127], 1);
        }
    }
    __syncthreads();

    // phase 2: exclusive scan of 128 bins (2 waves) — R22-identical
    {
        int v = (tid < 128) ? hist[tid] : 0;
        int inc = v;
        #pragma unroll
        for (int off = 1; off < 64; off <<= 1) {
            int t = __shfl_up(inc, off);
            if (lane >= off) inc += t;
        }
        if (tid < 128 && lane == 63) wsum[wid] = inc;
        __syncthreads();
        if (tid < 128) {
            int excl = inc - v + (wid ? wsum[0] : 0);
            begs[tid] = excl;
            cur[tid]  = excl;
            if (tid == 127) begs[128] = excl + v;
        }
        __syncthreads();
    }

    // phase 3: scatter own-half src from regs into sorted LDS
    #pragma unroll
    for (int k = 0; k < 20; ++k) {
        if (ev[k] != 0xFFFFFFFFu) {
            int p = atomicAdd(&cur[(ev[k] >> 17) & 127], 1);
            if (p < CAP_H) sorted[p] = ev[k] & 0x1FFFFu;
        }
    }
    if (et != 0xFFFFFFFFu) {
        int p = atomicAdd(&cur[(et >> 17) & 127], 1);
        if (p < CAP_H) sorted[p] = et & 0x1FFFFu;
    }
    __syncthreads();

    // phase 4: gather — 8-lane group per node, 2 nodes per group (R22-identical)
    const int grp = tid >> 3;                  // 0..63
    const int c   = tid & 7;                   // uint4 col 0..7
    const float4 b0 = ((const float4*)b)[c * 2];
    const float4 b1 = ((const float4*)b)[c * 2 + 1];
    const int node0 = bk * BUCKET_NODES + (int)h * 128;

    #pragma unroll
    for (int half = 0; half < 2; ++half) {
        const int n    = grp + half * 64;
        const int node = node0 + n;
        if (node < N_NODES) {
            int jb = begs[n], je = begs[n + 1];
            const int dg = je - jb;            // true in-degree
            if (je > CAP_H) je = CAP_H;
            if (jb > je) jb = je;
            float a0 = 0, a1 = 0, a2 = 0, a3 = 0, a4 = 0, a5 = 0, a6 = 0, a7 = 0;
            int j = jb;
            for (; j + 4 <= je; j += 4) {      // 4 edges in flight
                int s0 = (int)sorted[j];
                int s1 = (int)sorted[j + 1];
                int s2 = (int)sorted[j + 2];
                int s3 = (int)sorted[j + 3];
                float r0 = rsq_out[s0], r1 = rsq_out[s1];
                float r2 = rsq_out[s2], r3 = rsq_out[s3];
                uint4 u0 = sxw4[(long)s0 * 8 + c];
                uint4 u1 = sxw4[(long)s1 * 8 + c];
                uint4 u2 = sxw4[(long)s2 * 8 + c];
                uint4 u3 = sxw4[(long)s3 * 8 + c];
                ACCG(u0, r0) ACCG(u1, r1) ACCG(u2, r2) ACCG(u3, r3)
            }
            for (; j < je; ++j) {
                int s = (int)sorted[j];
                float rs = rsq_out[s];
                uint4 u = sxw4[(long)s * 8 + c];
                ACCG(u, rs)
            }
            float s = rsqrtf((float)(dg < 1 ? 1 : dg));
            float4 o0, o1;
            o0.x = fmaxf(fmaf(a0, s, b0.x), 0.0f);
            o0.y = fmaxf(fmaf(a1, s, b0.y), 0.0f);
            o0.z = fmaxf(fmaf(a2, s, b0.z), 0.0f);
            o0.w = fmaxf(fmaf(a3, s, b0.w), 0.0f);
            o1.x = fmaxf(fmaf(a4, s, b1.x), 0.0f);
            o1.y = fmaxf(fmaf(a5, s, b1.y), 0.0f);
            o1.z = fmaxf(fmaf(a6, s, b1.z), 0.0f);
            o1.w = fmaxf(fmaf(a7, s, b1.w), 0.0f);
            float4* orow = (float4*)(out + (long)node * OUT_F);
            orow[c * 2]     = o0;
            orow[c * 2 + 1] = o1;
        }
    }
}

extern "C" void kernel_launch(void* const* d_in, const int* in_sizes, int n_in,
                              void* d_out, int out_size, void* d_ws, size_t ws_size,
                              hipStream_t stream) {
    const float* in_feat = (const float*)d_in[0];
    const int*   src     = (const int*)d_in[1];
    const int*   dst     = (const int*)d_in[2];
    const float* W       = (const float*)d_in[3];
    const float* b       = (const float*)d_in[4];
    float*       out     = (float*)d_out;

    // ws: sxw bf16 [N*64] (12.8MB) | rsq_out [N] | bucket_cnt [NB] | bucket_cnt2 [NB]
    //   | pairs [NB*CAPB u32] (16MB) | sbytes [NB*CAPB] (4MB)
    __hip_bfloat16* sxw         = (__hip_bfloat16*)d_ws;
    float*          rsq_out     = (float*)(sxw + (size_t)N_NODES * OUT_F);
    int*            bucket_cnt  = (int*)(rsq_out + N_NODES);
    int*            bucket_cnt2 = bucket_cnt + NB;
    unsigned*       pairs       = (unsigned*)(bucket_cnt2 + NB + 2);  // 16B-align pad
    unsigned char*  sbytes      = (unsigned char*)(pairs + (size_t)NB * CAPB);

    hipMemsetAsync(bucket_cnt, 0, 2 * (size_t)NB * sizeof(int), stream);

    pg_kernel<<<PG_GRID, 512, 0, stream>>>(src, dst, bucket_cnt, bucket_cnt2,
                                           pairs, sbytes, in_feat, W, sxw);

    count_kernel<<<NB, 512, 0, stream>>>(sbytes, bucket_cnt2, rsq_out);

    sg_kernel<<<2 * NB, 512, 0, stream>>>(pairs, bucket_cnt, rsq_out,
                                          (const uint4*)sxw, b, out);
}